// Round 21
// baseline (70.460 us; speedup 1.0000x reference)
//
#include <hip/hip_runtime.h>
#include <hip/hip_bf16.h>

#define B_ 4
#define C_ 256
#define N_ 4096
#define K_ 16
#define QB 64
#define FSCALE 1.2011224087864498f   // sqrt(log2(e)) -> QK^T comes out in log2 domain
#define EXPA 8388608.0f              // 2^23
#define EXPB 1065101558.0f           // (127 - 0.030)*2^23  (Schraudolph, balanced +/-3% rel err)

typedef float f32x4 __attribute__((ext_vector_type(4)));
typedef float f32x16 __attribute__((ext_vector_type(16)));
typedef short s16x8 __attribute__((ext_vector_type(8)));
typedef int   i32x4 __attribute__((ext_vector_type(4)));
typedef int   i32x2 __attribute__((ext_vector_type(2)));

__device__ __forceinline__ short f2bf(float f) {
  union { float f; unsigned u; } v; v.f = f;
  unsigned r = v.u + 0x7fffu + ((v.u >> 16) & 1u);
  return (short)(r >> 16);
}

// LDS-only barrier: waits ds ops (lgkmcnt) but leaves global loads (vmcnt) IN FLIGHT across the
// barrier (T4: __syncthreads would drain vmcnt(0) and kill all prefetches). sched_barrier(0)
// fences compiler motion around the inline-asm wait (guide rule #18).
__device__ __forceinline__ void bar_lds_only() {
  asm volatile("s_waitcnt lgkmcnt(0)" ::: "memory");
  __builtin_amdgcn_sched_barrier(0);
  __builtin_amdgcn_s_barrier();
  __builtin_amdgcn_sched_barrier(0);
}

// ---------------- pass 1 (fused single-pass): x read ONCE -> fT + vtP ----------------
// Block = (b, 64-n tile), grid 256. Phase 1: conv partials (f32, identical arithmetic/order to
// the old prep) + bf16 x staged to swizzled LDS tile t. Phase 2: fT reduce + vtP pack from t
// (identical rounding/layout to the old packv). w1t and pr share one LDS region phase-wise.
__global__ __launch_bounds__(256) void pre(const float* __restrict__ x,
                                           const float* __restrict__ w1,
                                           const float* __restrict__ b1,
                                           short* __restrict__ fT,
                                           short* __restrict__ vtP) {
  __shared__ __align__(16) char sm[50176];   // t 32KB | region B 17.4KB (w1t ph1 / pr ph2)
  short* t   = (short*)sm;                   // [256 c][64 n] shorts, 8-short-block XOR swizzle
  float* w1t = (float*)(sm + 32768);         // [256][16] f32 (phase 1 only)
  float* pr  = (float*)(sm + 32768);         // [4][64][17] f32 (phase 2, same region)
  const int tid = threadIdx.x;
  const int b = blockIdx.x >> 6;
  const int n0 = (blockIdx.x & 63) * 64;
  for (int i = tid; i < C_ * K_; i += 256) {
    int k = i >> 8, c = i & 255;
    w1t[c * K_ + k] = w1[i];
  }
  __syncthreads();
  const int nl = tid & 63;
  const int cch = tid >> 6;
  const float* xp = x + ((size_t)b * C_ + cch * 64) * N_ + n0 + nl;
  float acc[K_];
#pragma unroll
  for (int k = 0; k < K_; k++) acc[k] = 0.f;
  for (int cc = 0; cc < 64; cc++) {
    const int c = cch * 64 + cc;
    float v = xp[(size_t)cc * N_];
    t[c * 64 + (nl ^ ((c & 7) * 8))] = f2bf(v);
    const f32x4* wp = (const f32x4*)(&w1t[c * K_]);
#pragma unroll
    for (int qq = 0; qq < 4; qq++) {
      f32x4 wv = wp[qq];
#pragma unroll
      for (int j = 0; j < 4; j++) acc[qq * 4 + j] += wv[j] * v;
    }
  }
  __syncthreads();           // w1t reads done (region becomes pr), t complete
#pragma unroll
  for (int k = 0; k < K_; k++) pr[(cch * 64 + nl) * 17 + k] = acc[k];
  __syncthreads();
  // fT: 1024 outputs = 64n x 16k
#pragma unroll
  for (int jj = 0; jj < 4; jj++) {
    int o = tid + jj * 256;
    int on = o >> 4, ok = o & 15;
    float s = b1[ok] + pr[(0 * 64 + on) * 17 + ok] + pr[(1 * 64 + on) * 17 + ok] +
              pr[(2 * 64 + on) * 17 + ok] + pr[(3 * 64 + on) * 17 + ok];
    fT[((size_t)b * N_ + n0 + on) * K_ + ok] = f2bf(s * FSCALE);
  }
  // vtP: thread = c, 8 g-groups (4 m16 x 2 hi within the 64-n span)
  {
    const int c = tid;
    const int swz = (c & 7) * 8;
#pragma unroll
    for (int g = 0; g < 8; g++) {
      const int m16 = g >> 1, hi = g & 1;
      i32x2 a  = *(const i32x2*)(&t[c * 64 + ((m16 * 16 + hi * 4) ^ swz)]);
      i32x2 bq = *(const i32x2*)(&t[c * 64 + ((m16 * 16 + 8 + hi * 4) ^ swz)]);
      i32x4 vv = {a[0], a[1], bq[0], bq[1]};
      const size_t gg = (size_t)b * 512 + (n0 >> 3) + m16 * 2 + hi;
      *(i32x4*)(vtP + (gg * 256 + c) * 8) = vv;
    }
  }
}

// ---------------- pass 2: R20 structure + LDS-only barriers + cross-barrier V prefetch -------
// 16 waves = h(2) x u(8); production (mt_p=u>>1, nt_p=u&1) of P(si+1) in registers overlapped
// with PV(si); PV c-span u*32 both nt (V loaded once). NEW: in-loop barriers wait lgkmcnt ONLY
// (V/K global prefetches survive the barrier), and next si's mt=0 V fragments are prefetched
// into registers before the barrier pair — PV never cold-starts on L2.
__global__ __launch_bounds__(1024) void flash18(const float* __restrict__ x,
                                                const short* __restrict__ vtP,
                                                const short* __restrict__ fT,
                                                float* __restrict__ out) {
  __shared__ __align__(16) char lds[65536];
  const int tid = threadIdx.x;
  const int l = tid & 63;
  const int w = tid >> 6;
  const int h = w >> 3;
  const int u = w & 7;
  const int mt_p = u >> 1;
  const int nt_p = u & 1;
  const int hi = l >> 5;
  const int q = l & 31;
  const int id = blockIdx.x;
  const int b = id & 3;            // XCD (id&7) -> fixed batch (vtP[b] = 2MB < 4MB L2)
  const int n0 = (id >> 2) * QB;

  const short* fTb = fT + (size_t)b * N_ * K_;
  const int mh0 = h * 2048;

  const s16x8 qf = *(const s16x8*)(fTb + (size_t)(n0 + nt_p * 32 + q) * K_ + hi * 8);
  const short* pkb = fTb + (size_t)(mh0 + mt_p * 64 + q) * K_ + hi * 8;
  const short* pvb = vtP + (((size_t)b * 512 + (mh0 >> 4) * 2 + hi) * 256 + u * 32 + q) * 8;

  char* pwr = lds + ((h * 2 + nt_p) * 4 + mt_p) * 4096 + hi * 512 + q * 16;
  const int prdO = hi * 512 + q * 16;

  f32x16 zero16 = {};
  f32x16 acc0 = zero16, acc1 = zero16;   // acc0 = nt0, acc1 = nt1 (same 32-c span)
  float lrun = 0.f;

  // ---- prologue: produce P(0), write, full barrier; prefetch K(1) and V(si=0, mt=0) ----
  {
    s16x8 k0 = *(const s16x8*)(pkb);
    s16x8 k1 = *(const s16x8*)(pkb + 32 * K_);
    f32x16 st0 = __builtin_amdgcn_mfma_f32_32x32x16_bf16(k0, qf, zero16, 0, 0, 0);
    f32x16 st1 = __builtin_amdgcn_mfma_f32_32x32x16_bf16(k1, qf, zero16, 0, 0, 0);
    int sd0[8], sd1[8];
    float ps0 = 0.f, ps1 = 0.f, ps2 = 0.f, ps3 = 0.f;
#pragma unroll
    for (int s2 = 0; s2 < 8; s2++) {
      int ia = (int)(st0[2 * s2] * EXPA + EXPB);
      int ib = (int)(st0[2 * s2 + 1] * EXPA + EXPB);
      ps0 += __int_as_float(ia);
      ps1 += __int_as_float(ib);
      sd0[s2] = (int)__builtin_amdgcn_perm((unsigned)ib, (unsigned)ia, 0x07060302u);
    }
#pragma unroll
    for (int s2 = 0; s2 < 8; s2++) {
      int ia = (int)(st1[2 * s2] * EXPA + EXPB);
      int ib = (int)(st1[2 * s2 + 1] * EXPA + EXPB);
      ps2 += __int_as_float(ia);
      ps3 += __int_as_float(ib);
      sd1[s2] = (int)__builtin_amdgcn_perm((unsigned)ib, (unsigned)ia, 0x07060302u);
    }
    lrun += (ps0 + ps1) + (ps2 + ps3);
    *(i32x4*)(pwr)        = (i32x4){sd0[0], sd0[1], sd0[2], sd0[3]};
    *(i32x4*)(pwr + 1024) = (i32x4){sd0[4], sd0[5], sd0[6], sd0[7]};
    *(i32x4*)(pwr + 2048) = (i32x4){sd1[0], sd1[1], sd1[2], sd1[3]};
    *(i32x4*)(pwr + 3072) = (i32x4){sd1[4], sd1[5], sd1[6], sd1[7]};
  }
  __syncthreads();
  s16x8 kf0 = *(const s16x8*)(pkb + 256 * K_);
  s16x8 kf1 = *(const s16x8*)(pkb + 256 * K_ + 32 * K_);
  s16x8 vc0 = *(const s16x8*)(pvb);
  s16x8 vc1 = *(const s16x8*)(pvb + 4096);
  s16x8 vc2 = *(const s16x8*)(pvb + 8192);
  s16x8 vc3 = *(const s16x8*)(pvb + 12288);

  for (int si = 0; si < 8; ++si) {
    const float lsc = (si < 7) ? 1.f : 0.f;
    const short* pkn = pkb + (size_t)((si + 2 < 7 ? si + 2 : 7) * 256) * K_;
    const short* pvn = pvb + (size_t)((si < 7 ? si + 1 : 7) * 4) * 16384;  // next si, mt=0

    __builtin_amdgcn_s_setprio(1);

    // ---- production of P(si+1) in registers (clamped dummy at si=7) ----
    f32x16 st0 = __builtin_amdgcn_mfma_f32_32x32x16_bf16(kf0, qf, zero16, 0, 0, 0);
    f32x16 st1 = __builtin_amdgcn_mfma_f32_32x32x16_bf16(kf1, qf, zero16, 0, 0, 0);
    s16x8 nk0 = *(const s16x8*)(pkn);
    s16x8 nk1 = *(const s16x8*)(pkn + 32 * K_);
    // cross-barrier V prefetch: next si's mt=0 fragments (consumed after 2 raw barriers)
    s16x8 nv0 = *(const s16x8*)(pvn);
    s16x8 nv1 = *(const s16x8*)(pvn + 4096);
    s16x8 nv2 = *(const s16x8*)(pvn + 8192);
    s16x8 nv3 = *(const s16x8*)(pvn + 12288);
    int sd0[8], sd1[8];
    float ps0 = 0.f, ps1 = 0.f, ps2 = 0.f, ps3 = 0.f;
#pragma unroll
    for (int s2 = 0; s2 < 8; s2++) {
      int ia = (int)(st0[2 * s2] * EXPA + EXPB);
      int ib = (int)(st0[2 * s2 + 1] * EXPA + EXPB);
      ps0 += __int_as_float(ia);
      ps1 += __int_as_float(ib);
      sd0[s2] = (int)__builtin_amdgcn_perm((unsigned)ib, (unsigned)ia, 0x07060302u);
    }
#pragma unroll
    for (int s2 = 0; s2 < 8; s2++) {
      int ia = (int)(st1[2 * s2] * EXPA + EXPB);
      int ib = (int)(st1[2 * s2 + 1] * EXPA + EXPB);
      ps2 += __int_as_float(ia);
      ps3 += __int_as_float(ib);
      sd1[s2] = (int)__builtin_amdgcn_perm((unsigned)ib, (unsigned)ia, 0x07060302u);
    }
    lrun += lsc * ((ps0 + ps1) + (ps2 + ps3));

    // ---- PV(si): mt=0 from carried regs (no load); mt=1..3 load inline ----
#pragma unroll
    for (int mt = 0; mt < 4; ++mt) {
      s16x8 vA0, vA1, vA2, vA3;
      if (mt == 0) {
        vA0 = vc0; vA1 = vc1; vA2 = vc2; vA3 = vc3;
      } else {
        const short* pv = pvb + (size_t)(si * 4 + mt) * 16384;
        vA0 = *(const s16x8*)(pv);
        vA1 = *(const s16x8*)(pv + 4096);
        vA2 = *(const s16x8*)(pv + 8192);
        vA3 = *(const s16x8*)(pv + 12288);
      }
      const char* p0 = lds + ((h * 2 + 0) * 4 + mt) * 4096 + prdO;
      const char* p1 = lds + ((h * 2 + 1) * 4 + mt) * 4096 + prdO;
      s16x8 pa0 = __builtin_bit_cast(s16x8, *(const i32x4*)(p0));
      s16x8 pb0 = __builtin_bit_cast(s16x8, *(const i32x4*)(p1));
      acc0 = __builtin_amdgcn_mfma_f32_32x32x16_bf16(vA0, pa0, acc0, 0, 0, 0);
      acc1 = __builtin_amdgcn_mfma_f32_32x32x16_bf16(vA0, pb0, acc1, 0, 0, 0);
      s16x8 pa1 = __builtin_bit_cast(s16x8, *(const i32x4*)(p0 + 1024));
      s16x8 pb1 = __builtin_bit_cast(s16x8, *(const i32x4*)(p1 + 1024));
      acc0 = __builtin_amdgcn_mfma_f32_32x32x16_bf16(vA1, pa1, acc0, 0, 0, 0);
      acc1 = __builtin_amdgcn_mfma_f32_32x32x16_bf16(vA1, pb1, acc1, 0, 0, 0);
      s16x8 pa2 = __builtin_bit_cast(s16x8, *(const i32x4*)(p0 + 2048));
      s16x8 pb2 = __builtin_bit_cast(s16x8, *(const i32x4*)(p1 + 2048));
      acc0 = __builtin_amdgcn_mfma_f32_32x32x16_bf16(vA2, pa2, acc0, 0, 0, 0);
      acc1 = __builtin_amdgcn_mfma_f32_32x32x16_bf16(vA2, pb2, acc1, 0, 0, 0);
      s16x8 pa3 = __builtin_bit_cast(s16x8, *(const i32x4*)(p0 + 3072));
      s16x8 pb3 = __builtin_bit_cast(s16x8, *(const i32x4*)(p1 + 3072));
      acc0 = __builtin_amdgcn_mfma_f32_32x32x16_bf16(vA3, pa3, acc0, 0, 0, 0);
      acc1 = __builtin_amdgcn_mfma_f32_32x32x16_bf16(vA3, pb3, acc1, 0, 0, 0);
    }
    __builtin_amdgcn_s_setprio(0);

    // barrier #1: all waves done ds_reading P(si). My P ds_reads completed via MFMA reg-deps;
    // V/K global prefetches stay in flight (no vmcnt drain).
    bar_lds_only();

    *(i32x4*)(pwr)        = (i32x4){sd0[0], sd0[1], sd0[2], sd0[3]};
    *(i32x4*)(pwr + 1024) = (i32x4){sd0[4], sd0[5], sd0[6], sd0[7]};
    *(i32x4*)(pwr + 2048) = (i32x4){sd1[0], sd1[1], sd1[2], sd1[3]};
    *(i32x4*)(pwr + 3072) = (i32x4){sd1[4], sd1[5], sd1[6], sd1[7]};

    // barrier #2: my sd ds_writes visible (lgkmcnt(0)) before any wave reads P(si+1).
    bar_lds_only();

    kf0 = nk0; kf1 = nk1;
    vc0 = nv0; vc1 = nv1; vc2 = nv2; vc3 = nv3;
  }

  // hi-partner combine of own-tile column sums
  lrun += __shfl_xor(lrun, 32);

  // ---------------- epilogue ----------------
  float* mlb = (float*)lds;             // [16 waves][64 lanes] (P no longer needed)
  mlb[w * 64 + l] = lrun;
  __syncthreads();
  float L0 = 0.f, L1 = 0.f;
#pragma unroll
  for (int hh = 0; hh < 2; ++hh)
#pragma unroll
    for (int mt = 0; mt < 4; ++mt) {
      L0 += mlb[(hh * 8 + mt * 2 + 0) * 64 + l];
      L1 += mlb[(hh * 8 + mt * 2 + 1) * 64 + l];
    }
  __syncthreads();
  char* xch = lds;                      // [8 u][64 l][128B], swizzled
  const int xbase = (u * 64 + l) * 128;
  if (h == 1) {
#pragma unroll
    for (int i = 0; i < 8; i++) {
      f32x4 v;
#pragma unroll
      for (int r = 0; r < 4; r++) v[r] = (i >> 2) ? acc1[(i & 3) * 4 + r] : acc0[(i & 3) * 4 + r];
      *(f32x4*)(xch + xbase + ((i * 16) ^ ((l & 7) << 4))) = v;
    }
  }
  __syncthreads();
  if (h == 0) {
    const float inv0 = 0.1f / L0;
    const float inv1 = 0.1f / L1;
#pragma unroll
    for (int i = 0; i < 8; i++) {
      f32x4 po = *(const f32x4*)(xch + xbase + ((i * 16) ^ ((l & 7) << 4)));
      const int p_ = i & 3;
      const int ntw = i >> 2;
      const float inv = ntw ? inv1 : inv0;
      const int n = n0 + ntw * 32 + q;
      const int cbase = u * 32 + p_ * 8 + hi * 4;
#pragma unroll
      for (int r = 0; r < 4; r++) {
        const float own = ntw ? acc1[p_ * 4 + r] : acc0[p_ * 4 + r];
        const size_t idx = ((size_t)b * C_ + (cbase + r)) * N_ + n;
        out[idx] = x[idx] + (own + po[r]) * inv;
      }
    }
  }
}

extern "C" void kernel_launch(void* const* d_in, const int* in_sizes, int n_in,
                              void* d_out, int out_size, void* d_ws, size_t ws_size,
                              hipStream_t stream) {
  const float* x  = (const float*)d_in[0];
  const float* w1 = (const float*)d_in[1];
  const float* b1 = (const float*)d_in[2];
  float* out = (float*)d_out;
  short* fT  = (short*)d_ws;                         // [B][N][16] bf16, 512KB
  short* vtP = (short*)((char*)d_ws + 512 * 1024);   // [B][512][256][8] bf16, 8MB
  pre<<<dim3(256), dim3(256), 0, stream>>>(x, w1, b1, fT, vtP);
  flash18<<<dim3(256), dim3(1024), 0, stream>>>(x, vtP, fT, out);
}

// Round 22
// 59.469 us; speedup vs baseline: 1.1848x; 1.1848x over previous
//
#include <hip/hip_runtime.h>
#include <hip/hip_bf16.h>

#define B_ 4
#define C_ 256
#define N_ 4096
#define K_ 16
#define QB 64
#define FSCALE 1.2011224087864498f   // sqrt(log2(e)) -> QK^T comes out in log2 domain
#define EXPA 8388608.0f              // 2^23
#define EXPB 1065101558.0f           // (127 - 0.030)*2^23  (Schraudolph, balanced +/-3% rel err)

typedef float f32x4 __attribute__((ext_vector_type(4)));
typedef float f32x16 __attribute__((ext_vector_type(16)));
typedef short s16x8 __attribute__((ext_vector_type(8)));
typedef int   i32x4 __attribute__((ext_vector_type(4)));
typedef int   i32x2 __attribute__((ext_vector_type(2)));

__device__ __forceinline__ short f2bf(float f) {
  union { float f; unsigned u; } v; v.f = f;
  unsigned r = v.u + 0x7fffu + ((v.u >> 16) & 1u);
  return (short)(r >> 16);
}

// ---------------- pass 1 (fused single-pass, occupancy-fixed): x read ONCE -> fT + vtP --------
// Grid 512 = b(4) x 128 32-n tiles; 256 threads; 50KB LDS -> 2 blocks/CU (8 waves/CU).
// Phase 1: stage bf16 x tile to t[256][34] (+1-dword row pad: 17-dword stride, gcd(17,32)=1 ->
// conflict-free) + f32 conv partials (8 chunks of 32 c). Phase 2: fT reduce + vtP pack from t.
// vtP element mapping / f2bf rounding identical to the proven packv.
__global__ __launch_bounds__(256) void pre(const float* __restrict__ x,
                                           const float* __restrict__ w1,
                                           const float* __restrict__ b1,
                                           short* __restrict__ fT,
                                           short* __restrict__ vtP) {
  __shared__ __align__(16) short t[256 * 34];     // 17.4KB, padded rows
  __shared__ float w1t[C_ * K_];                  // 16KB
  __shared__ float pr[8][32][17];                 // 17.4KB
  const int tid = threadIdx.x;
  const int b = blockIdx.x >> 7;
  const int n0 = (blockIdx.x & 127) * 32;
  for (int i = tid; i < C_ * K_; i += 256) {
    int k = i >> 8, c = i & 255;
    w1t[c * K_ + k] = w1[i];
  }
  __syncthreads();
  const int nl = tid & 31;
  const int cch = tid >> 5;        // 0..7, 32 c each
  const float* xp = x + ((size_t)(b * C_ + cch * 32)) * N_ + n0 + nl;
  float acc[K_];
#pragma unroll
  for (int k = 0; k < K_; k++) acc[k] = 0.f;
  for (int cc = 0; cc < 32; cc++) {
    const int c = cch * 32 + cc;
    float v = xp[(size_t)cc * N_];
    t[c * 34 + nl] = f2bf(v);
    const f32x4* wp = (const f32x4*)(&w1t[c * K_]);
#pragma unroll
    for (int qq = 0; qq < 4; qq++) {
      f32x4 wv = wp[qq];
#pragma unroll
      for (int j = 0; j < 4; j++) acc[qq * 4 + j] += wv[j] * v;
    }
  }
#pragma unroll
  for (int k = 0; k < K_; k++) pr[cch][nl][k] = acc[k];
  __syncthreads();               // t and pr complete
  // fT: 512 outputs = 32n x 16k
#pragma unroll
  for (int jj = 0; jj < 2; jj++) {
    int o = tid + jj * 256;
    int on = o >> 4, ok = o & 15;
    float s = b1[ok];
#pragma unroll
    for (int u = 0; u < 8; u++) s += pr[u][on][ok];
    fT[((size_t)b * N_ + n0 + on) * K_ + ok] = f2bf(s * FSCALE);
  }
  // vtP: thread = c; 32-n span = 2 local m16 x 2 hi groups
  {
    const int c = tid;
#pragma unroll
    for (int g = 0; g < 4; g++) {
      const int lm = g >> 1, hi = g & 1;
      i32x2 a  = *(const i32x2*)(&t[c * 34 + lm * 16 + hi * 4]);
      i32x2 bq = *(const i32x2*)(&t[c * 34 + lm * 16 + 8 + hi * 4]);
      i32x4 vv = {a[0], a[1], bq[0], bq[1]};
      const size_t gg = (size_t)b * 512 + (n0 >> 3) + 2 * lm + hi;
      *(i32x4*)(vtP + (gg * 256 + c) * 8) = vv;
    }
  }
}

// ---------------- pass 2: R20 flash17, byte-exact (proven 50.4us) ----------------
// 16 waves = h(2) x u(8); production (mt_p=u>>1, nt_p=u&1) of P(si+1) in registers overlapped
// with PV(si) in one scheduling region; PV c-span u*32 both nt (V loaded once); plain
// __syncthreads barriers (compiler-scheduled; R21 lesson: sched_barrier pins regress).
__global__ __launch_bounds__(1024) void flash17(const float* __restrict__ x,
                                                const short* __restrict__ vtP,
                                                const short* __restrict__ fT,
                                                float* __restrict__ out) {
  __shared__ __align__(16) char lds[65536];
  const int tid = threadIdx.x;
  const int l = tid & 63;
  const int w = tid >> 6;
  const int h = w >> 3;
  const int u = w & 7;
  const int mt_p = u >> 1;
  const int nt_p = u & 1;
  const int hi = l >> 5;
  const int q = l & 31;
  const int id = blockIdx.x;
  const int b = id & 3;            // XCD (id&7) -> fixed batch (vtP[b] = 2MB < 4MB L2)
  const int n0 = (id >> 2) * QB;

  const short* fTb = fT + (size_t)b * N_ * K_;
  const int mh0 = h * 2048;

  const s16x8 qf = *(const s16x8*)(fTb + (size_t)(n0 + nt_p * 32 + q) * K_ + hi * 8);
  const short* pkb = fTb + (size_t)(mh0 + mt_p * 64 + q) * K_ + hi * 8;
  const short* pvb = vtP + (((size_t)b * 512 + (mh0 >> 4) * 2 + hi) * 256 + u * 32 + q) * 8;

  char* pwr = lds + ((h * 2 + nt_p) * 4 + mt_p) * 4096 + hi * 512 + q * 16;
  const int prdO = hi * 512 + q * 16;

  f32x16 zero16 = {};
  f32x16 acc0 = zero16, acc1 = zero16;   // acc0 = nt0, acc1 = nt1 (same 32-c span)
  float lrun = 0.f;

  // ---- prologue: produce P(0), write, bar ----
  {
    s16x8 k0 = *(const s16x8*)(pkb);
    s16x8 k1 = *(const s16x8*)(pkb + 32 * K_);
    f32x16 st0 = __builtin_amdgcn_mfma_f32_32x32x16_bf16(k0, qf, zero16, 0, 0, 0);
    f32x16 st1 = __builtin_amdgcn_mfma_f32_32x32x16_bf16(k1, qf, zero16, 0, 0, 0);
    int sd0[8], sd1[8];
    float ps0 = 0.f, ps1 = 0.f, ps2 = 0.f, ps3 = 0.f;
#pragma unroll
    for (int s2 = 0; s2 < 8; s2++) {
      int ia = (int)(st0[2 * s2] * EXPA + EXPB);
      int ib = (int)(st0[2 * s2 + 1] * EXPA + EXPB);
      ps0 += __int_as_float(ia);
      ps1 += __int_as_float(ib);
      sd0[s2] = (int)__builtin_amdgcn_perm((unsigned)ib, (unsigned)ia, 0x07060302u);
    }
#pragma unroll
    for (int s2 = 0; s2 < 8; s2++) {
      int ia = (int)(st1[2 * s2] * EXPA + EXPB);
      int ib = (int)(st1[2 * s2 + 1] * EXPA + EXPB);
      ps2 += __int_as_float(ia);
      ps3 += __int_as_float(ib);
      sd1[s2] = (int)__builtin_amdgcn_perm((unsigned)ib, (unsigned)ia, 0x07060302u);
    }
    lrun += (ps0 + ps1) + (ps2 + ps3);
    *(i32x4*)(pwr)        = (i32x4){sd0[0], sd0[1], sd0[2], sd0[3]};
    *(i32x4*)(pwr + 1024) = (i32x4){sd0[4], sd0[5], sd0[6], sd0[7]};
    *(i32x4*)(pwr + 2048) = (i32x4){sd1[0], sd1[1], sd1[2], sd1[3]};
    *(i32x4*)(pwr + 3072) = (i32x4){sd1[4], sd1[5], sd1[6], sd1[7]};
  }
  __syncthreads();
  // K for production of P(1)
  s16x8 kf0 = *(const s16x8*)(pkb + 256 * K_);
  s16x8 kf1 = *(const s16x8*)(pkb + 256 * K_ + 32 * K_);

  for (int si = 0; si < 8; ++si) {
    const float lsc = (si < 7) ? 1.f : 0.f;
    const short* pkn = pkb + (size_t)((si + 2 < 7 ? si + 2 : 7) * 256) * K_;

    __builtin_amdgcn_s_setprio(1);

    // ---- production of P(si+1) in registers (clamped dummy at si=7) ----
    f32x16 st0 = __builtin_amdgcn_mfma_f32_32x32x16_bf16(kf0, qf, zero16, 0, 0, 0);
    f32x16 st1 = __builtin_amdgcn_mfma_f32_32x32x16_bf16(kf1, qf, zero16, 0, 0, 0);
    s16x8 nk0 = *(const s16x8*)(pkn);
    s16x8 nk1 = *(const s16x8*)(pkn + 32 * K_);
    int sd0[8], sd1[8];
    float ps0 = 0.f, ps1 = 0.f, ps2 = 0.f, ps3 = 0.f;
#pragma unroll
    for (int s2 = 0; s2 < 8; s2++) {
      int ia = (int)(st0[2 * s2] * EXPA + EXPB);
      int ib = (int)(st0[2 * s2 + 1] * EXPA + EXPB);
      ps0 += __int_as_float(ia);
      ps1 += __int_as_float(ib);
      sd0[s2] = (int)__builtin_amdgcn_perm((unsigned)ib, (unsigned)ia, 0x07060302u);
    }
#pragma unroll
    for (int s2 = 0; s2 < 8; s2++) {
      int ia = (int)(st1[2 * s2] * EXPA + EXPB);
      int ib = (int)(st1[2 * s2 + 1] * EXPA + EXPB);
      ps2 += __int_as_float(ia);
      ps3 += __int_as_float(ib);
      sd1[s2] = (int)__builtin_amdgcn_perm((unsigned)ib, (unsigned)ia, 0x07060302u);
    }
    lrun += lsc * ((ps0 + ps1) + (ps2 + ps3));

    // ---- PV(si): V loaded once per (mt,m16), applied to both nt's P ----
#pragma unroll
    for (int mt = 0; mt < 4; ++mt) {
      const short* pv = pvb + (size_t)(si * 4 + mt) * 16384;
      s16x8 vA0 = *(const s16x8*)(pv);
      s16x8 vA1 = *(const s16x8*)(pv + 4096);
      s16x8 vA2 = *(const s16x8*)(pv + 8192);
      s16x8 vA3 = *(const s16x8*)(pv + 12288);
      const char* p0 = lds + ((h * 2 + 0) * 4 + mt) * 4096 + prdO;
      const char* p1 = lds + ((h * 2 + 1) * 4 + mt) * 4096 + prdO;
      s16x8 pa0 = __builtin_bit_cast(s16x8, *(const i32x4*)(p0));
      s16x8 pb0 = __builtin_bit_cast(s16x8, *(const i32x4*)(p1));
      acc0 = __builtin_amdgcn_mfma_f32_32x32x16_bf16(vA0, pa0, acc0, 0, 0, 0);
      acc1 = __builtin_amdgcn_mfma_f32_32x32x16_bf16(vA0, pb0, acc1, 0, 0, 0);
      s16x8 pa1 = __builtin_bit_cast(s16x8, *(const i32x4*)(p0 + 1024));
      s16x8 pb1 = __builtin_bit_cast(s16x8, *(const i32x4*)(p1 + 1024));
      acc0 = __builtin_amdgcn_mfma_f32_32x32x16_bf16(vA1, pa1, acc0, 0, 0, 0);
      acc1 = __builtin_amdgcn_mfma_f32_32x32x16_bf16(vA1, pb1, acc1, 0, 0, 0);
      s16x8 pa2 = __builtin_bit_cast(s16x8, *(const i32x4*)(p0 + 2048));
      s16x8 pb2 = __builtin_bit_cast(s16x8, *(const i32x4*)(p1 + 2048));
      acc0 = __builtin_amdgcn_mfma_f32_32x32x16_bf16(vA2, pa2, acc0, 0, 0, 0);
      acc1 = __builtin_amdgcn_mfma_f32_32x32x16_bf16(vA2, pb2, acc1, 0, 0, 0);
      s16x8 pa3 = __builtin_bit_cast(s16x8, *(const i32x4*)(p0 + 3072));
      s16x8 pb3 = __builtin_bit_cast(s16x8, *(const i32x4*)(p1 + 3072));
      acc0 = __builtin_amdgcn_mfma_f32_32x32x16_bf16(vA3, pa3, acc0, 0, 0, 0);
      acc1 = __builtin_amdgcn_mfma_f32_32x32x16_bf16(vA3, pb3, acc1, 0, 0, 0);
    }
    __builtin_amdgcn_s_setprio(0);
    __syncthreads();   // all waves done reading P(si)

    *(i32x4*)(pwr)        = (i32x4){sd0[0], sd0[1], sd0[2], sd0[3]};
    *(i32x4*)(pwr + 1024) = (i32x4){sd0[4], sd0[5], sd0[6], sd0[7]};
    *(i32x4*)(pwr + 2048) = (i32x4){sd1[0], sd1[1], sd1[2], sd1[3]};
    *(i32x4*)(pwr + 3072) = (i32x4){sd1[4], sd1[5], sd1[6], sd1[7]};
    __syncthreads();   // P(si+1) visible

    kf0 = nk0; kf1 = nk1;
  }

  // hi-partner combine of own-tile column sums
  lrun += __shfl_xor(lrun, 32);

  // ---------------- epilogue ----------------
  float* mlb = (float*)lds;             // [16 waves][64 lanes] (P no longer needed)
  mlb[w * 64 + l] = lrun;
  __syncthreads();
  float L0 = 0.f, L1 = 0.f;
#pragma unroll
  for (int hh = 0; hh < 2; ++hh)
#pragma unroll
    for (int mt = 0; mt < 4; ++mt) {
      L0 += mlb[(hh * 8 + mt * 2 + 0) * 64 + l];
      L1 += mlb[(hh * 8 + mt * 2 + 1) * 64 + l];
    }
  __syncthreads();
  char* xch = lds;                      // [8 u][64 l][128B], swizzled
  const int xbase = (u * 64 + l) * 128;
  if (h == 1) {
#pragma unroll
    for (int i = 0; i < 8; i++) {
      f32x4 v;
#pragma unroll
      for (int r = 0; r < 4; r++) v[r] = (i >> 2) ? acc1[(i & 3) * 4 + r] : acc0[(i & 3) * 4 + r];
      *(f32x4*)(xch + xbase + ((i * 16) ^ ((l & 7) << 4))) = v;
    }
  }
  __syncthreads();
  if (h == 0) {
    const float inv0 = 0.1f / L0;
    const float inv1 = 0.1f / L1;
#pragma unroll
    for (int i = 0; i < 8; i++) {
      f32x4 po = *(const f32x4*)(xch + xbase + ((i * 16) ^ ((l & 7) << 4)));
      const int p_ = i & 3;
      const int ntw = i >> 2;
      const float inv = ntw ? inv1 : inv0;
      const int n = n0 + ntw * 32 + q;
      const int cbase = u * 32 + p_ * 8 + hi * 4;
#pragma unroll
      for (int r = 0; r < 4; r++) {
        const float own = ntw ? acc1[p_ * 4 + r] : acc0[p_ * 4 + r];
        const size_t idx = ((size_t)b * C_ + (cbase + r)) * N_ + n;
        out[idx] = x[idx] + (own + po[r]) * inv;
      }
    }
  }
}

extern "C" void kernel_launch(void* const* d_in, const int* in_sizes, int n_in,
                              void* d_out, int out_size, void* d_ws, size_t ws_size,
                              hipStream_t stream) {
  const float* x  = (const float*)d_in[0];
  const float* w1 = (const float*)d_in[1];
  const float* b1 = (const float*)d_in[2];
  float* out = (float*)d_out;
  short* fT  = (short*)d_ws;                         // [B][N][16] bf16, 512KB
  short* vtP = (short*)((char*)d_ws + 512 * 1024);   // [B][512][256][8] bf16, 8MB
  pre<<<dim3(512), dim3(256), 0, stream>>>(x, w1, b1, fT, vtP);
  flash17<<<dim3(256), dim3(1024), 0, stream>>>(x, vtP, fT, out);
}

// Round 23
// 58.983 us; speedup vs baseline: 1.1946x; 1.0082x over previous
//
#include <hip/hip_runtime.h>
#include <hip/hip_bf16.h>

#define B_ 4
#define C_ 256
#define N_ 4096
#define K_ 16
#define QB 64
#define FSCALE 1.2011224087864498f   // sqrt(log2(e)) -> QK^T comes out in log2 domain
#define EXPA 8388608.0f              // 2^23
#define EXPB 1065101558.0f           // (127 - 0.030)*2^23  (Schraudolph, balanced +/-3% rel err)

typedef float f32x4 __attribute__((ext_vector_type(4)));
typedef float f32x16 __attribute__((ext_vector_type(16)));
typedef short s16x8 __attribute__((ext_vector_type(8)));
typedef int   i32x4 __attribute__((ext_vector_type(4)));
typedef int   i32x2 __attribute__((ext_vector_type(2)));

__device__ __forceinline__ short f2bf(float f) {
  union { float f; unsigned u; } v; v.f = f;
  unsigned r = v.u + 0x7fffu + ((v.u >> 16) & 1u);
  return (short)(r >> 16);
}

// ---------------- pass 1 (fused single-pass, R22 frozen): x read ONCE -> fT + vtP --------
__global__ __launch_bounds__(256) void pre(const float* __restrict__ x,
                                           const float* __restrict__ w1,
                                           const float* __restrict__ b1,
                                           short* __restrict__ fT,
                                           short* __restrict__ vtP) {
  __shared__ __align__(16) short t[256 * 34];     // 17.4KB, padded rows (17-dword stride)
  __shared__ float w1t[C_ * K_];                  // 16KB
  __shared__ float pr[8][32][17];                 // 17.4KB
  const int tid = threadIdx.x;
  const int b = blockIdx.x >> 7;
  const int n0 = (blockIdx.x & 127) * 32;
  for (int i = tid; i < C_ * K_; i += 256) {
    int k = i >> 8, c = i & 255;
    w1t[c * K_ + k] = w1[i];
  }
  __syncthreads();
  const int nl = tid & 31;
  const int cch = tid >> 5;        // 0..7, 32 c each
  const float* xp = x + ((size_t)(b * C_ + cch * 32)) * N_ + n0 + nl;
  float acc[K_];
#pragma unroll
  for (int k = 0; k < K_; k++) acc[k] = 0.f;
  for (int cc = 0; cc < 32; cc++) {
    const int c = cch * 32 + cc;
    float v = xp[(size_t)cc * N_];
    t[c * 34 + nl] = f2bf(v);
    const f32x4* wp = (const f32x4*)(&w1t[c * K_]);
#pragma unroll
    for (int qq = 0; qq < 4; qq++) {
      f32x4 wv = wp[qq];
#pragma unroll
      for (int j = 0; j < 4; j++) acc[qq * 4 + j] += wv[j] * v;
    }
  }
#pragma unroll
  for (int k = 0; k < K_; k++) pr[cch][nl][k] = acc[k];
  __syncthreads();
#pragma unroll
  for (int jj = 0; jj < 2; jj++) {
    int o = tid + jj * 256;
    int on = o >> 4, ok = o & 15;
    float s = b1[ok];
#pragma unroll
    for (int u = 0; u < 8; u++) s += pr[u][on][ok];
    fT[((size_t)b * N_ + n0 + on) * K_ + ok] = f2bf(s * FSCALE);
  }
  {
    const int c = tid;
#pragma unroll
    for (int g = 0; g < 4; g++) {
      const int lm = g >> 1, hi = g & 1;
      i32x2 a  = *(const i32x2*)(&t[c * 34 + lm * 16 + hi * 4]);
      i32x2 bq = *(const i32x2*)(&t[c * 34 + lm * 16 + 8 + hi * 4]);
      i32x4 vv = {a[0], a[1], bq[0], bq[1]};
      const size_t gg = (size_t)b * 512 + (n0 >> 3) + 2 * lm + hi;
      *(i32x4*)(vtP + (gg * 256 + c) * 8) = vv;
    }
  }
}

// ---------------- pass 2: R20 flash17 + explicit early V-load placement ----------------
// Identical structure; ONLY change: mt=0/1 V loads issued at region top (covered by the
// production QK+exp ~1000cy), mt=2/3 at PV start (covered by the first 16 PV MFMAs). This
// front-loads the L2-V stream so delivery overlaps compute instead of stalling each mt-group.
__global__ __launch_bounds__(1024) void flash19(const float* __restrict__ x,
                                                const short* __restrict__ vtP,
                                                const short* __restrict__ fT,
                                                float* __restrict__ out) {
  __shared__ __align__(16) char lds[65536];
  const int tid = threadIdx.x;
  const int l = tid & 63;
  const int w = tid >> 6;
  const int h = w >> 3;
  const int u = w & 7;
  const int mt_p = u >> 1;
  const int nt_p = u & 1;
  const int hi = l >> 5;
  const int q = l & 31;
  const int id = blockIdx.x;
  const int b = id & 3;            // XCD (id&7) -> fixed batch (vtP[b] = 2MB < 4MB L2)
  const int n0 = (id >> 2) * QB;

  const short* fTb = fT + (size_t)b * N_ * K_;
  const int mh0 = h * 2048;

  const s16x8 qf = *(const s16x8*)(fTb + (size_t)(n0 + nt_p * 32 + q) * K_ + hi * 8);
  const short* pkb = fTb + (size_t)(mh0 + mt_p * 64 + q) * K_ + hi * 8;
  const short* pvb = vtP + (((size_t)b * 512 + (mh0 >> 4) * 2 + hi) * 256 + u * 32 + q) * 8;

  char* pwr = lds + ((h * 2 + nt_p) * 4 + mt_p) * 4096 + hi * 512 + q * 16;
  const int prdO = hi * 512 + q * 16;

  f32x16 zero16 = {};
  f32x16 acc0 = zero16, acc1 = zero16;   // acc0 = nt0, acc1 = nt1 (same 32-c span)
  float lrun = 0.f;

  // ---- prologue: produce P(0), write, bar ----
  {
    s16x8 k0 = *(const s16x8*)(pkb);
    s16x8 k1 = *(const s16x8*)(pkb + 32 * K_);
    f32x16 st0 = __builtin_amdgcn_mfma_f32_32x32x16_bf16(k0, qf, zero16, 0, 0, 0);
    f32x16 st1 = __builtin_amdgcn_mfma_f32_32x32x16_bf16(k1, qf, zero16, 0, 0, 0);
    int sd0[8], sd1[8];
    float ps0 = 0.f, ps1 = 0.f, ps2 = 0.f, ps3 = 0.f;
#pragma unroll
    for (int s2 = 0; s2 < 8; s2++) {
      int ia = (int)(st0[2 * s2] * EXPA + EXPB);
      int ib = (int)(st0[2 * s2 + 1] * EXPA + EXPB);
      ps0 += __int_as_float(ia);
      ps1 += __int_as_float(ib);
      sd0[s2] = (int)__builtin_amdgcn_perm((unsigned)ib, (unsigned)ia, 0x07060302u);
    }
#pragma unroll
    for (int s2 = 0; s2 < 8; s2++) {
      int ia = (int)(st1[2 * s2] * EXPA + EXPB);
      int ib = (int)(st1[2 * s2 + 1] * EXPA + EXPB);
      ps2 += __int_as_float(ia);
      ps3 += __int_as_float(ib);
      sd1[s2] = (int)__builtin_amdgcn_perm((unsigned)ib, (unsigned)ia, 0x07060302u);
    }
    lrun += (ps0 + ps1) + (ps2 + ps3);
    *(i32x4*)(pwr)        = (i32x4){sd0[0], sd0[1], sd0[2], sd0[3]};
    *(i32x4*)(pwr + 1024) = (i32x4){sd0[4], sd0[5], sd0[6], sd0[7]};
    *(i32x4*)(pwr + 2048) = (i32x4){sd1[0], sd1[1], sd1[2], sd1[3]};
    *(i32x4*)(pwr + 3072) = (i32x4){sd1[4], sd1[5], sd1[6], sd1[7]};
  }
  __syncthreads();
  // K for production of P(1)
  s16x8 kf0 = *(const s16x8*)(pkb + 256 * K_);
  s16x8 kf1 = *(const s16x8*)(pkb + 256 * K_ + 32 * K_);

  for (int si = 0; si < 8; ++si) {
    const float lsc = (si < 7) ? 1.f : 0.f;
    const short* pkn = pkb + (size_t)((si + 2 < 7 ? si + 2 : 7) * 256) * K_;
    const short* pvsi = pvb + (size_t)(si * 4) * 16384;

    __builtin_amdgcn_s_setprio(1);

    // ---- V loads for mt=0,1 FIRST: production below covers their L2 latency ----
    s16x8 v00 = *(const s16x8*)(pvsi);
    s16x8 v01 = *(const s16x8*)(pvsi + 4096);
    s16x8 v02 = *(const s16x8*)(pvsi + 8192);
    s16x8 v03 = *(const s16x8*)(pvsi + 12288);
    s16x8 v10 = *(const s16x8*)(pvsi + 16384);
    s16x8 v11 = *(const s16x8*)(pvsi + 16384 + 4096);
    s16x8 v12 = *(const s16x8*)(pvsi + 16384 + 8192);
    s16x8 v13 = *(const s16x8*)(pvsi + 16384 + 12288);

    // ---- production of P(si+1) in registers (clamped dummy at si=7) ----
    f32x16 st0 = __builtin_amdgcn_mfma_f32_32x32x16_bf16(kf0, qf, zero16, 0, 0, 0);
    f32x16 st1 = __builtin_amdgcn_mfma_f32_32x32x16_bf16(kf1, qf, zero16, 0, 0, 0);
    s16x8 nk0 = *(const s16x8*)(pkn);
    s16x8 nk1 = *(const s16x8*)(pkn + 32 * K_);
    int sd0[8], sd1[8];
    float ps0 = 0.f, ps1 = 0.f, ps2 = 0.f, ps3 = 0.f;
#pragma unroll
    for (int s2 = 0; s2 < 8; s2++) {
      int ia = (int)(st0[2 * s2] * EXPA + EXPB);
      int ib = (int)(st0[2 * s2 + 1] * EXPA + EXPB);
      ps0 += __int_as_float(ia);
      ps1 += __int_as_float(ib);
      sd0[s2] = (int)__builtin_amdgcn_perm((unsigned)ib, (unsigned)ia, 0x07060302u);
    }
#pragma unroll
    for (int s2 = 0; s2 < 8; s2++) {
      int ia = (int)(st1[2 * s2] * EXPA + EXPB);
      int ib = (int)(st1[2 * s2 + 1] * EXPA + EXPB);
      ps2 += __int_as_float(ia);
      ps3 += __int_as_float(ib);
      sd1[s2] = (int)__builtin_amdgcn_perm((unsigned)ib, (unsigned)ia, 0x07060302u);
    }
    lrun += lsc * ((ps0 + ps1) + (ps2 + ps3));

    // ---- V loads for mt=2,3: PV's first 16 MFMAs cover them ----
    s16x8 v20 = *(const s16x8*)(pvsi + 2 * 16384);
    s16x8 v21 = *(const s16x8*)(pvsi + 2 * 16384 + 4096);
    s16x8 v22 = *(const s16x8*)(pvsi + 2 * 16384 + 8192);
    s16x8 v23 = *(const s16x8*)(pvsi + 2 * 16384 + 12288);
    s16x8 v30 = *(const s16x8*)(pvsi + 3 * 16384);
    s16x8 v31 = *(const s16x8*)(pvsi + 3 * 16384 + 4096);
    s16x8 v32 = *(const s16x8*)(pvsi + 3 * 16384 + 8192);
    s16x8 v33 = *(const s16x8*)(pvsi + 3 * 16384 + 12288);

    // ---- PV(si): 4 mt blocks, named V vars (no per-mt load stalls) ----
#define PV_MT(MT, VA, VB, VC, VD)                                                  \
    {                                                                              \
      const char* p0 = lds + ((h * 2 + 0) * 4 + (MT)) * 4096 + prdO;               \
      const char* p1 = lds + ((h * 2 + 1) * 4 + (MT)) * 4096 + prdO;               \
      s16x8 pa0 = __builtin_bit_cast(s16x8, *(const i32x4*)(p0));                  \
      s16x8 pb0 = __builtin_bit_cast(s16x8, *(const i32x4*)(p1));                  \
      acc0 = __builtin_amdgcn_mfma_f32_32x32x16_bf16(VA, pa0, acc0, 0, 0, 0);      \
      acc1 = __builtin_amdgcn_mfma_f32_32x32x16_bf16(VA, pb0, acc1, 0, 0, 0);      \
      s16x8 pa1 = __builtin_bit_cast(s16x8, *(const i32x4*)(p0 + 1024));           \
      s16x8 pb1 = __builtin_bit_cast(s16x8, *(const i32x4*)(p1 + 1024));           \
      acc0 = __builtin_amdgcn_mfma_f32_32x32x16_bf16(VB, pa1, acc0, 0, 0, 0);      \
      acc1 = __builtin_amdgcn_mfma_f32_32x32x16_bf16(VB, pb1, acc1, 0, 0, 0);      \
      s16x8 pa2 = __builtin_bit_cast(s16x8, *(const i32x4*)(p0 + 2048));           \
      s16x8 pb2 = __builtin_bit_cast(s16x8, *(const i32x4*)(p1 + 2048));           \
      acc0 = __builtin_amdgcn_mfma_f32_32x32x16_bf16(VC, pa2, acc0, 0, 0, 0);      \
      acc1 = __builtin_amdgcn_mfma_f32_32x32x16_bf16(VC, pb2, acc1, 0, 0, 0);      \
      s16x8 pa3 = __builtin_bit_cast(s16x8, *(const i32x4*)(p0 + 3072));           \
      s16x8 pb3 = __builtin_bit_cast(s16x8, *(const i32x4*)(p1 + 3072));           \
      acc0 = __builtin_amdgcn_mfma_f32_32x32x16_bf16(VD, pa3, acc0, 0, 0, 0);      \
      acc1 = __builtin_amdgcn_mfma_f32_32x32x16_bf16(VD, pb3, acc1, 0, 0, 0);      \
    }
    PV_MT(0, v00, v01, v02, v03)
    PV_MT(1, v10, v11, v12, v13)
    PV_MT(2, v20, v21, v22, v23)
    PV_MT(3, v30, v31, v32, v33)
#undef PV_MT

    __builtin_amdgcn_s_setprio(0);
    __syncthreads();   // all waves done reading P(si)

    *(i32x4*)(pwr)        = (i32x4){sd0[0], sd0[1], sd0[2], sd0[3]};
    *(i32x4*)(pwr + 1024) = (i32x4){sd0[4], sd0[5], sd0[6], sd0[7]};
    *(i32x4*)(pwr + 2048) = (i32x4){sd1[0], sd1[1], sd1[2], sd1[3]};
    *(i32x4*)(pwr + 3072) = (i32x4){sd1[4], sd1[5], sd1[6], sd1[7]};
    __syncthreads();   // P(si+1) visible

    kf0 = nk0; kf1 = nk1;
  }

  // hi-partner combine of own-tile column sums
  lrun += __shfl_xor(lrun, 32);

  // ---------------- epilogue ----------------
  float* mlb = (float*)lds;             // [16 waves][64 lanes] (P no longer needed)
  mlb[w * 64 + l] = lrun;
  __syncthreads();
  float L0 = 0.f, L1 = 0.f;
#pragma unroll
  for (int hh = 0; hh < 2; ++hh)
#pragma unroll
    for (int mt = 0; mt < 4; ++mt) {
      L0 += mlb[(hh * 8 + mt * 2 + 0) * 64 + l];
      L1 += mlb[(hh * 8 + mt * 2 + 1) * 64 + l];
    }
  __syncthreads();
  char* xch = lds;                      // [8 u][64 l][128B], swizzled
  const int xbase = (u * 64 + l) * 128;
  if (h == 1) {
#pragma unroll
    for (int i = 0; i < 8; i++) {
      f32x4 v;
#pragma unroll
      for (int r = 0; r < 4; r++) v[r] = (i >> 2) ? acc1[(i & 3) * 4 + r] : acc0[(i & 3) * 4 + r];
      *(f32x4*)(xch + xbase + ((i * 16) ^ ((l & 7) << 4))) = v;
    }
  }
  __syncthreads();
  if (h == 0) {
    const float inv0 = 0.1f / L0;
    const float inv1 = 0.1f / L1;
#pragma unroll
    for (int i = 0; i < 8; i++) {
      f32x4 po = *(const f32x4*)(xch + xbase + ((i * 16) ^ ((l & 7) << 4)));
      const int p_ = i & 3;
      const int ntw = i >> 2;
      const float inv = ntw ? inv1 : inv0;
      const int n = n0 + ntw * 32 + q;
      const int cbase = u * 32 + p_ * 8 + hi * 4;
#pragma unroll
      for (int r = 0; r < 4; r++) {
        const float own = ntw ? acc1[p_ * 4 + r] : acc0[p_ * 4 + r];
        const size_t idx = ((size_t)b * C_ + (cbase + r)) * N_ + n;
        out[idx] = x[idx] + (own + po[r]) * inv;
      }
    }
  }
}

extern "C" void kernel_launch(void* const* d_in, const int* in_sizes, int n_in,
                              void* d_out, int out_size, void* d_ws, size_t ws_size,
                              hipStream_t stream) {
  const float* x  = (const float*)d_in[0];
  const float* w1 = (const float*)d_in[1];
  const float* b1 = (const float*)d_in[2];
  float* out = (float*)d_out;
  short* fT  = (short*)d_ws;                         // [B][N][16] bf16, 512KB
  short* vtP = (short*)((char*)d_ws + 512 * 1024);   // [B][512][256][8] bf16, 8MB
  pre<<<dim3(512), dim3(256), 0, stream>>>(x, w1, b1, fT, vtP);
  flash19<<<dim3(256), dim3(1024), 0, stream>>>(x, vtP, fT, out);
}